// Round 1
// baseline (254.556 us; speedup 1.0000x reference)
//
#include <hip/hip_runtime.h>

// Cutout: x [B,C,H,W] fp32, zero a LENGTH x LENGTH box centered at (cy[b], cx[b])
// across all channels. B=256, C=3, H=W=224, n_holes=1, LENGTH=16.
// Memory-bound elementwise op: one float4 per thread, fully coalesced.

#define B_ 256
#define C_ 3
#define H_ 224
#define W_ 224
#define HALF 8
#define W4_ (W_ / 4)           // 56
#define TOTAL4 (B_ * C_ * H_ * W4_)  // 9,633,792

__global__ __launch_bounds__(256) void cutout_kernel(
    const float* __restrict__ x,
    const int* __restrict__ cy,
    const int* __restrict__ cx,
    float* __restrict__ out) {
    int idx = blockIdx.x * blockDim.x + threadIdx.x;
    if (idx >= TOTAL4) return;

    // idx = ((b*C + c)*H + y)*W4 + x4
    int x4 = idx % W4_;
    int t  = idx / W4_;
    int y  = t % H_;
    int t2 = t / H_;          // b*C + c
    int b  = t2 / C_;

    float4 v = reinterpret_cast<const float4*>(x)[idx];

    int cyb = cy[b];
    int cxb = cx[b];
    // box: [cyb-HALF, cyb+HALF) x [cxb-HALF, cxb+HALF)
    if (y >= cyb - HALF && y < cyb + HALF) {
        int x0 = x4 * 4;
        int lo = cxb - HALF;
        int hi = cxb + HALF;
        if (x0     >= lo && x0     < hi) v.x = 0.0f;
        if (x0 + 1 >= lo && x0 + 1 < hi) v.y = 0.0f;
        if (x0 + 2 >= lo && x0 + 2 < hi) v.z = 0.0f;
        if (x0 + 3 >= lo && x0 + 3 < hi) v.w = 0.0f;
    }

    reinterpret_cast<float4*>(out)[idx] = v;
}

extern "C" void kernel_launch(void* const* d_in, const int* in_sizes, int n_in,
                              void* d_out, int out_size, void* d_ws, size_t ws_size,
                              hipStream_t stream) {
    const float* x  = (const float*)d_in[0];
    const int*   cy = (const int*)d_in[1];   // [1, B]
    const int*   cx = (const int*)d_in[2];   // [1, B]
    float* out = (float*)d_out;

    const int threads = 256;
    const int blocks  = (TOTAL4 + threads - 1) / threads;  // 37632
    cutout_kernel<<<blocks, threads, 0, stream>>>(x, cy, cx, out);
}

// Round 3
// 249.530 us; speedup vs baseline: 1.0201x; 1.0201x over previous
//
#include <hip/hip_runtime.h>

// Cutout: x [B,C,H,W] fp32, zero a LENGTH x LENGTH box centered at (cy[b], cx[b])
// across all channels. B=256, C=3, H=W=224, n_holes=1, LENGTH=16.
//
// Memory-bound streaming op. Floor: 154 MB read + 154 MB write ~= 49 us @ 6.3 TB/s.
// Layout: grid.y = plane index (b*C+c) -> b is wave-uniform (SALU div),
// grid.x * 256 + tid = float4 index within the 224x224 plane (12544 = 49*256,
// exact -> no bounds check). Only one per-thread magic-div (by 56) remains.
// Nontemporal loads/stores: data is single-touch, skip L2 pollution.
// NOTE: HIP float4 is a struct; nontemporal builtins need a clang ext_vector.

typedef float floatx4 __attribute__((ext_vector_type(4)));

#define B_ 256
#define C_ 3
#define H_ 224
#define W_ 224
#define HALF 8
#define W4_ (W_ / 4)                 // 56
#define PLANE4 (H_ * W4_)            // 12544 float4 per plane
#define BLOCKS_X (PLANE4 / 256)      // 49, exact

__global__ __launch_bounds__(256) void cutout_kernel(
    const floatx4* __restrict__ x,
    const int* __restrict__ cy,
    const int* __restrict__ cx,
    floatx4* __restrict__ out) {
    const int plane = blockIdx.y;                       // b*C + c, uniform
    const int b = plane / C_;                           // uniform -> SALU
    const int ip = blockIdx.x * 256 + threadIdx.x;      // [0, PLANE4)

    const int y  = ip / W4_;                            // one magic-div
    const int x4 = ip - y * W4_;

    const long gidx = (long)plane * PLANE4 + ip;
    floatx4 v = __builtin_nontemporal_load(&x[gidx]);

    const int cyb = cy[b];                              // uniform scalar load
    const int cxb = cx[b];

    if (y >= cyb - HALF && y < cyb + HALF) {
        const int x0 = x4 * 4;
        const int lo = cxb - HALF;
        const int hi = cxb + HALF;
        v.x = (x0     >= lo && x0     < hi) ? 0.0f : v.x;
        v.y = (x0 + 1 >= lo && x0 + 1 < hi) ? 0.0f : v.y;
        v.z = (x0 + 2 >= lo && x0 + 2 < hi) ? 0.0f : v.z;
        v.w = (x0 + 3 >= lo && x0 + 3 < hi) ? 0.0f : v.w;
    }

    __builtin_nontemporal_store(v, &out[gidx]);
}

extern "C" void kernel_launch(void* const* d_in, const int* in_sizes, int n_in,
                              void* d_out, int out_size, void* d_ws, size_t ws_size,
                              hipStream_t stream) {
    const floatx4* x  = (const floatx4*)d_in[0];
    const int*     cy = (const int*)d_in[1];   // [1, B]
    const int*     cx = (const int*)d_in[2];   // [1, B]
    floatx4* out = (floatx4*)d_out;

    dim3 grid(BLOCKS_X, B_ * C_);              // 49 x 768 = 37632 blocks
    cutout_kernel<<<grid, 256, 0, stream>>>(x, cy, cx, out);
}